// Round 2
// baseline (14123.283 us; speedup 1.0000x reference)
//
#include <hip/hip_runtime.h>

#define T_FULL 1024
#define NBATCH 64
#define IDIM   512
#define NCH    256
#define GD     768
#define ODIM   3
#define NBLK   16

typedef _Float16 half8   __attribute__((ext_vector_type(8)));
typedef float    floatx4 __attribute__((ext_vector_type(4)));
typedef unsigned int uintx4 __attribute__((ext_vector_type(4)));
typedef unsigned int uintx2 __attribute__((ext_vector_type(2)));

__device__ __forceinline__ float sigmoidf_(float x) { return 1.0f / (1.0f + __expf(-x)); }
__device__ __forceinline__ float tanhf_(float x)    { return 1.0f - 2.0f / (__expf(2.0f * x) + 1.0f); }
__device__ __forceinline__ floatx4 splat4(float v) { floatx4 r; r[0]=v; r[1]=v; r[2]=v; r[3]=v; return r; }

__device__ __forceinline__ half8 cvt8(const float* __restrict__ p) {
  floatx4 a = *(const floatx4*)p;
  floatx4 b = *(const floatx4*)(p + 4);
  half8 h;
  h[0]=(_Float16)a[0]; h[1]=(_Float16)a[1]; h[2]=(_Float16)a[2]; h[3]=(_Float16)a[3];
  h[4]=(_Float16)b[0]; h[5]=(_Float16)b[1]; h[6]=(_Float16)b[2]; h[7]=(_Float16)b[3];
  return h;
}

// ---------------------------------------------------------------------------
// Precompute GEMM: for k<512 part of layer-0 input gates.
// Output layout: Xw[((t*16 + (c>>4))*3 + gate)*1024 + b*16 + (c&15)]  (f16)
// so each rec block's per-step slice is a dense 6KB chunk.
// ---------------------------------------------------------------------------
__global__ __launch_bounds__(256)
void xw_gemm(const float* __restrict__ x, const float* __restrict__ w_ih0,
             _Float16* __restrict__ Xw, int t0, int Tc) {
  __shared__ _Float16 As[128 * 32];
  __shared__ _Float16 Bs[128 * 32];
  const int tid  = threadIdx.x;
  const int lane = tid & 63;
  const int wave = tid >> 6;
  const int lq = lane >> 4, lc = lane & 15;
  const int wm = wave >> 1, wn = wave & 1;

  const int sr = tid >> 1;
  const int sh = (tid & 1) * 16;
  const int m  = blockIdx.x * 128 + sr;
  const float* arow = x + ((size_t)(m & 63) * T_FULL + (size_t)(t0 + (m >> 6))) * IDIM;
  const float* brow = w_ih0 + (size_t)(blockIdx.y * 128 + sr) * GD;

  floatx4 acc[4][4];
  #pragma unroll
  for (int i = 0; i < 4; ++i)
    #pragma unroll
    for (int j = 0; j < 4; ++j) acc[i][j] = splat4(0.f);

  for (int kk = 0; kk < IDIM; kk += 32) {
    __syncthreads();
    #pragma unroll
    for (int kb = 0; kb < 2; ++kb) {
      const int k0  = sh + kb * 8;
      const int gis = (k0 >> 3) ^ ((sr >> 2) & 3);
      *(half8*)((char*)As + sr * 64 + gis * 16) = cvt8(arow + kk + k0);
      *(half8*)((char*)Bs + sr * 64 + gis * 16) = cvt8(brow + kk + k0);
    }
    __syncthreads();
    half8 af[4], bf[4];
    #pragma unroll
    for (int ms = 0; ms < 4; ++ms) {
      const int r = wm * 64 + ms * 16 + lc;
      af[ms] = *(const half8*)((char*)As + r * 64 + ((lq ^ ((r >> 2) & 3)) * 16));
    }
    #pragma unroll
    for (int ns = 0; ns < 4; ++ns) {
      const int r = wn * 64 + ns * 16 + lc;
      bf[ns] = *(const half8*)((char*)Bs + r * 64 + ((lq ^ ((r >> 2) & 3)) * 16));
    }
    #pragma unroll
    for (int ms = 0; ms < 4; ++ms)
      #pragma unroll
      for (int ns = 0; ns < 4; ++ns)
        acc[ms][ns] = __builtin_amdgcn_mfma_f32_16x16x32_f16(af[ms], bf[ns], acc[ms][ns], 0, 0, 0);
  }

  #pragma unroll
  for (int ms = 0; ms < 4; ++ms)
    #pragma unroll
    for (int ns = 0; ns < 4; ++ns)
      #pragma unroll
      for (int q = 0; q < 4; ++q) {
        const int mloc = blockIdx.x * 128 + wm * 64 + ms * 16 + lq * 4 + q;
        const int gp   = blockIdx.y * 128 + wn * 64 + ns * 16 + lc;
        const int t = mloc >> 6, b = mloc & 63;
        const int gate = gp >> 8, cch = gp & 255;
        Xw[(((size_t)t * NBLK + (cch >> 4)) * 3 + gate) * 1024 + b * 16 + (cch & 15)]
            = (_Float16)acc[ms][ns][q];
      }
}

// ---------------------------------------------------------------------------
// LL packet exchange: packet = {dword0: 2 x f16 (channels 2k,2k+1 of batch b),
// dword1: tag = publish_step+1}. Stored/loaded with sc0 sc1 (device-coherent,
// bypasses non-coherent per-XCD L2) -> no fences, no barrier needed.
// Layout per parity: [64 b][128 pkt] * 8B = 64KB.
// ---------------------------------------------------------------------------
__device__ __forceinline__ void poll_group(const char* __restrict__ pb, int boff,
                                           unsigned exp, half8* __restrict__ out) {
  uintx4 A[16];
  int cap = 1 << 18;
  for (;;) {
    #pragma unroll
    for (int f = 0; f < 8; ++f) {
      const char* p0 = pb + boff + f * 128;
      asm volatile("global_load_dwordx4 %0, %1, off sc0 sc1"
                   : "=v"(A[2 * f]) : "v"(p0) : "memory");
      asm volatile("global_load_dwordx4 %0, %1, off sc0 sc1"
                   : "=v"(A[2 * f + 1]) : "v"(p0 + 16) : "memory");
    }
    asm volatile("s_waitcnt vmcnt(0)" ::: "memory");
    __builtin_amdgcn_sched_barrier(0);
    bool ok = true;
    #pragma unroll
    for (int j = 0; j < 16; ++j) ok = ok && (A[j].y == exp) && (A[j].w == exp);
    if (__all((int)ok) || --cap <= 0) break;
  }
  #pragma unroll
  for (int f = 0; f < 8; ++f) {
    uintx4 t;
    t.x = A[2 * f].x;     t.y = A[2 * f].z;
    t.z = A[2 * f + 1].x; t.w = A[2 * f + 1].z;
    out[f] = __builtin_bit_cast(half8, t);
  }
}

__device__ __forceinline__ void publish4(char* __restrict__ base, int wave, int lq, int lc,
                                         int blk, unsigned tag, const float* __restrict__ hv) {
  float pv[4];
  #pragma unroll
  for (int q = 0; q < 4; ++q) pv[q] = __shfl_xor(hv[q], 1, 64);
  unsigned dq[4];
  #pragma unroll
  for (int q = 0; q < 4; ++q) {
    _Float16 a = (_Float16)hv[q], p = (_Float16)pv[q];
    unsigned au = __builtin_bit_cast(unsigned short, a);
    unsigned pu = __builtin_bit_cast(unsigned short, p);
    dq[q] = (lc & 1) ? (pu | (au << 16)) : (au | (pu << 16));
  }
  const int q0 = (lc & 1) ? 2 : 0;
  #pragma unroll
  for (int s = 0; s < 2; ++s) {
    const int q = q0 + s;
    char* addr = base + (((wave * 16 + lq * 4 + q) * 128) + blk * 8 + (lc >> 1)) * 8;
    uintx2 v; v.x = dq[q]; v.y = tag;
    asm volatile("global_store_dwordx2 %0, %1, off sc0 sc1"
                 :: "v"(addr), "v"(v) : "memory");
  }
}

// ---------------------------------------------------------------------------
// Persistent recurrent kernel, free-running on LL data dependencies.
// 16 blocks x 256 threads; block owns 16 channels; wave owns 16 batches.
// ---------------------------------------------------------------------------
__global__ __launch_bounds__(256, 1)
void rec_step(const float* __restrict__ w_ih0, const float* __restrict__ w_hh0,
              const float* __restrict__ w_ih1, const float* __restrict__ w_hh1,
              const float* __restrict__ b_ih0, const float* __restrict__ b_hh0,
              const float* __restrict__ b_ih1, const float* __restrict__ b_hh1,
              const float* __restrict__ embed_w, const float* __restrict__ embed_b,
              const float* __restrict__ proj_w, const float* __restrict__ proj_b,
              const _Float16* __restrict__ Xw, float* __restrict__ out,
              char* h0b, char* h1b,
              int t0, int Tc, int lastChunk) {
  const int tid  = threadIdx.x;
  const int wave = tid >> 6;
  const int lane = tid & 63;
  const int lq = lane >> 4, lc = lane & 15;
  const int blk = blockIdx.x;
  const int c   = blk * 16 + lc;

  // ---- weights in registers (f16 MFMA fragments)
  half8 Whh0[3][8], Whh1[3][8], Wih1[3][8], Pj[8];
  #pragma unroll
  for (int g = 0; g < 3; ++g) {
    const int row = g * NCH + c;
    #pragma unroll
    for (int ks = 0; ks < 8; ++ks) {
      const int k0 = ks * 32 + lq * 8;
      Whh0[g][ks] = cvt8(w_hh0 + (size_t)row * NCH + k0);
      Whh1[g][ks] = cvt8(w_hh1 + (size_t)row * NCH + k0);
      Wih1[g][ks] = cvt8(w_ih1 + (size_t)row * NCH + k0);
    }
  }
  #pragma unroll
  for (int ks = 0; ks < 8; ++ks) {
    const int k0 = ks * 32 + lq * 8;
    half8 z;
    #pragma unroll
    for (int j = 0; j < 8; ++j) z[j] = (_Float16)0.f;
    Pj[ks] = (lc < 3) ? cvt8(proj_w + lc * NCH + k0) : z;
  }

  // ---- folded constants
  float Wce[3][3], bi0[3], bh0v[3], bi1v[3], bh1v[3];
  #pragma unroll
  for (int g = 0; g < 3; ++g) {
    const int row = g * NCH + c;
    float a0 = 0.f, a1 = 0.f, a2 = 0.f, ab = b_ih0[row];
    const float* wr = w_ih0 + (size_t)row * GD + IDIM;
    for (int k = 0; k < NCH; ++k) {
      const float w = wr[k];
      a0 += w * embed_w[k * 3 + 0];
      a1 += w * embed_w[k * 3 + 1];
      a2 += w * embed_w[k * 3 + 2];
      ab += w * embed_b[k];
    }
    Wce[g][0] = a0; Wce[g][1] = a1; Wce[g][2] = a2;
    bi0[g] = ab;
    bh0v[g] = b_hh0[row]; bi1v[g] = b_ih1[row]; bh1v[g] = b_hh1[row];
  }
  const float pb = (lc < 3) ? proj_b[lc] : 0.f;

  // ---- state
  float h0st[4] = {0.f, 0.f, 0.f, 0.f};
  float h1st[4] = {0.f, 0.f, 0.f, 0.f};
  if (t0 > 0) {
    const int rpo = ((t0 & 1) ^ 1) * 65536;
    const unsigned long long* p0 = (const unsigned long long*)(h0b + rpo);
    const unsigned long long* p1 = (const unsigned long long*)(h1b + rpo);
    #pragma unroll
    for (int q = 0; q < 4; ++q) {
      const int b   = wave * 16 + lq * 4 + q;
      const int idx = b * 128 + blk * 8 + (lc >> 1);
      unsigned d0 = (unsigned)p0[idx], d1 = (unsigned)p1[idx];
      unsigned short u0 = (lc & 1) ? (unsigned short)(d0 >> 16) : (unsigned short)(d0 & 0xffff);
      unsigned short u1 = (lc & 1) ? (unsigned short)(d1 >> 16) : (unsigned short)(d1 & 0xffff);
      h0st[q] = (float)__builtin_bit_cast(_Float16, u0);
      h1st[q] = (float)__builtin_bit_cast(_Float16, u1);
    }
  }

  const int boff = (wave * 16 + lc) * 1024 + lq * 32;  // fragment byte base
  floatx4 ag1l[3];
  half8 hf[8];

  for (int lt = 0; lt < Tc; ++lt) {
    const int gt = t0 + lt;
    const int rp = ((gt & 1) ^ 1) * 65536;
    const int wp = (gt & 1) * 65536;
    const unsigned expt = (unsigned)gt;

    // ======== PHASE 1 ========
    // issue Xw loads early (dense 6KB chunk per (t,blk)); overlap with polls
    const _Float16* xb = Xw + ((size_t)lt * NBLK + blk) * 3072;
    unsigned short xwu[3][4];
    #pragma unroll
    for (int g = 0; g < 3; ++g)
      #pragma unroll
      for (int q = 0; q < 4; ++q)
        xwu[g][q] = *(const unsigned short*)(xb + g * 1024 + (wave * 16 + lq * 4 + q) * 16 + lc);

    // h1(t-1): gh1 + v-pre (laggard source -> poll first)
    poll_group(h1b + rp, boff, expt, hf);
    floatx4 av = splat4(pb);
    #pragma unroll
    for (int g = 0; g < 3; ++g) ag1l[g] = splat4(bh1v[g]);
    #pragma unroll
    for (int ks = 0; ks < 8; ++ks) {
      #pragma unroll
      for (int g = 0; g < 3; ++g)
        ag1l[g] = __builtin_amdgcn_mfma_f32_16x16x32_f16(hf[ks], Whh1[g][ks], ag1l[g], 0, 0, 0);
      av = __builtin_amdgcn_mfma_f32_16x16x32_f16(hf[ks], Pj[ks], av, 0, 0, 0);
    }

    // h0(t-1): gh0
    poll_group(h0b + rp, boff, expt, hf);
    floatx4 ah0[3];
    #pragma unroll
    for (int g = 0; g < 3; ++g) ah0[g] = splat4(bh0v[g]);
    #pragma unroll
    for (int ks = 0; ks < 8; ++ks)
      #pragma unroll
      for (int g = 0; g < 3; ++g)
        ah0[g] = __builtin_amdgcn_mfma_f32_16x16x32_f16(hf[ks], Whh0[g][ks], ah0[g], 0, 0, 0);

    // v(t-1) redistribute + out write
    float vv0[4], vv1[4], vv2[4];
    if (gt == 0) {
      #pragma unroll
      for (int q = 0; q < 4; ++q) { vv0[q] = 0.f; vv1[q] = 0.f; vv2[q] = 0.f; }
    } else {
      float sv[4];
      #pragma unroll
      for (int q = 0; q < 4; ++q) sv[q] = (lc < 3) ? sigmoidf_(av[q]) : 0.f;
      if (blk == 0 && lc < 3) {
        #pragma unroll
        for (int q = 0; q < 4; ++q)
          out[((size_t)(wave * 16 + lq * 4 + q) * T_FULL + (gt - 1)) * ODIM + lc] = sv[q];
      }
      #pragma unroll
      for (int q = 0; q < 4; ++q) {
        vv0[q] = __shfl(sv[q], (lq << 4) + 0, 64);
        vv1[q] = __shfl(sv[q], (lq << 4) + 1, 64);
        vv2[q] = __shfl(sv[q], (lq << 4) + 2, 64);
      }
    }

    // layer-0 combine
    float h0n[4];
    #pragma unroll
    for (int q = 0; q < 4; ++q) {
      const float i_r = (float)__builtin_bit_cast(_Float16, xwu[0][q]) + bi0[0]
                        + vv0[q] * Wce[0][0] + vv1[q] * Wce[0][1] + vv2[q] * Wce[0][2];
      const float i_z = (float)__builtin_bit_cast(_Float16, xwu[1][q]) + bi0[1]
                        + vv0[q] * Wce[1][0] + vv1[q] * Wce[1][1] + vv2[q] * Wce[1][2];
      const float i_n = (float)__builtin_bit_cast(_Float16, xwu[2][q]) + bi0[2]
                        + vv0[q] * Wce[2][0] + vv1[q] * Wce[2][1] + vv2[q] * Wce[2][2];
      const float r = sigmoidf_(i_r + ah0[0][q]);
      const float z = sigmoidf_(i_z + ah0[1][q]);
      const float n = tanhf_(i_n + r * ah0[2][q]);
      h0n[q] = (1.f - z) * n + z * h0st[q];
      h0st[q] = h0n[q];
    }
    publish4(h0b + wp, wave, lq, lc, blk, (unsigned)(gt + 1), h0n);

    // ======== PHASE 2 ========
    poll_group(h0b + wp, boff, (unsigned)(gt + 1), hf);
    floatx4 ai1[3];
    #pragma unroll
    for (int g = 0; g < 3; ++g) ai1[g] = splat4(bi1v[g]);
    #pragma unroll
    for (int ks = 0; ks < 8; ++ks)
      #pragma unroll
      for (int g = 0; g < 3; ++g)
        ai1[g] = __builtin_amdgcn_mfma_f32_16x16x32_f16(hf[ks], Wih1[g][ks], ai1[g], 0, 0, 0);

    float h1n[4];
    #pragma unroll
    for (int q = 0; q < 4; ++q) {
      const float r = sigmoidf_(ai1[0][q] + ag1l[0][q]);
      const float z = sigmoidf_(ai1[1][q] + ag1l[1][q]);
      const float n = tanhf_(ai1[2][q] + r * ag1l[2][q]);
      h1n[q] = (1.f - z) * n + z * h1st[q];
      h1st[q] = h1n[q];
    }
    publish4(h1b + wp, wave, lq, lc, blk, (unsigned)(gt + 1), h1n);
  }

  // tail: final v(T-1)
  if (lastChunk && blk == 0) {
    poll_group(h1b + (((t0 + Tc - 1) & 1) * 65536), boff, (unsigned)(t0 + Tc), hf);
    floatx4 av = splat4(pb);
    #pragma unroll
    for (int ks = 0; ks < 8; ++ks)
      av = __builtin_amdgcn_mfma_f32_16x16x32_f16(hf[ks], Pj[ks], av, 0, 0, 0);
    if (lc < 3) {
      #pragma unroll
      for (int q = 0; q < 4; ++q)
        out[((size_t)(wave * 16 + lq * 4 + q) * T_FULL + (T_FULL - 1)) * ODIM + lc]
            = sigmoidf_(av[q]);
    }
  }
}

extern "C" void kernel_launch(void* const* d_in, const int* in_sizes, int n_in,
                              void* d_out, int out_size, void* d_ws, size_t ws_size,
                              hipStream_t stream) {
  const float* x       = (const float*)d_in[0];
  const float* embed_w = (const float*)d_in[1];
  const float* embed_b = (const float*)d_in[2];
  const float* w_ih0   = (const float*)d_in[3];
  const float* w_hh0   = (const float*)d_in[4];
  const float* b_ih0   = (const float*)d_in[5];
  const float* b_hh0   = (const float*)d_in[6];
  const float* w_ih1   = (const float*)d_in[7];
  const float* w_hh1   = (const float*)d_in[8];
  const float* b_ih1   = (const float*)d_in[9];
  const float* b_hh1   = (const float*)d_in[10];
  const float* proj_w  = (const float*)d_in[11];
  const float* proj_b  = (const float*)d_in[12];
  float* out = (float*)d_out;

  char* ws = (char*)d_ws;
  char* h0b = ws;                    // 2 parity x 64KB packets
  char* h1b = ws + 131072;           // 2 parity x 64KB packets
  _Float16* Xw = (_Float16*)(ws + 262144);

  const size_t per_t = (size_t)NBATCH * GD * sizeof(_Float16);  // 98304 B
  size_t xw_avail = (ws_size > 262144) ? (ws_size - 262144) : 0;
  long maxTc = (long)(xw_avail / per_t);
  int Tc = 2;
  while ((long)Tc * 2 <= maxTc && Tc * 2 <= T_FULL) Tc *= 2;

  // zero packet buffers (tag 0 == "step -1 valid, data 0")
  hipMemsetAsync(ws, 0, 262144, stream);

  for (int t0 = 0; t0 < T_FULL; t0 += Tc) {
    dim3 g1(Tc * NBATCH / 128, GD / 128);
    xw_gemm<<<g1, 256, 0, stream>>>(x, w_ih0, Xw, t0, Tc);
    rec_step<<<NBLK, 256, 0, stream>>>(w_ih0, w_hh0, w_ih1, w_hh1,
                                       b_ih0, b_hh0, b_ih1, b_hh1,
                                       embed_w, embed_b, proj_w, proj_b,
                                       Xw, out, h0b, h1b,
                                       t0, Tc, (t0 + Tc) >= T_FULL ? 1 : 0);
  }
}

// Round 4
// 12832.970 us; speedup vs baseline: 1.1005x; 1.1005x over previous
//
#include <hip/hip_runtime.h>

#define T_FULL 1024
#define NBATCH 64
#define IDIM   512
#define NCH    256
#define GD     768
#define ODIM   3
#define NBLK   16

typedef _Float16 half8   __attribute__((ext_vector_type(8)));
typedef float    floatx4 __attribute__((ext_vector_type(4)));
typedef unsigned int uintx4 __attribute__((ext_vector_type(4)));
typedef unsigned int uintx2 __attribute__((ext_vector_type(2)));

__device__ __forceinline__ float sigmoidf_(float x) { return 1.0f / (1.0f + __expf(-x)); }
__device__ __forceinline__ float tanhf_(float x)    { return 1.0f - 2.0f / (__expf(2.0f * x) + 1.0f); }
__device__ __forceinline__ floatx4 splat4(float v) { floatx4 r; r[0]=v; r[1]=v; r[2]=v; r[3]=v; return r; }

__device__ __forceinline__ half8 cvt8(const float* __restrict__ p) {
  floatx4 a = *(const floatx4*)p;
  floatx4 b = *(const floatx4*)(p + 4);
  half8 h;
  h[0]=(_Float16)a[0]; h[1]=(_Float16)a[1]; h[2]=(_Float16)a[2]; h[3]=(_Float16)a[3];
  h[4]=(_Float16)b[0]; h[5]=(_Float16)b[1]; h[6]=(_Float16)b[2]; h[7]=(_Float16)b[3];
  return h;
}

// ---------------------------------------------------------------------------
// Precompute GEMM (k<512 part of layer-0 input gates).
// Output layout: Xw[((t*16 + blk)*3 + gate)*1024 + b*16 + (c&15)]  (f16)
// ---------------------------------------------------------------------------
__global__ __launch_bounds__(256)
void xw_gemm(const float* __restrict__ x, const float* __restrict__ w_ih0,
             _Float16* __restrict__ Xw, int t0, int Tc) {
  __shared__ _Float16 As[128 * 32];
  __shared__ _Float16 Bs[128 * 32];
  const int tid  = threadIdx.x;
  const int lane = tid & 63;
  const int wave = tid >> 6;
  const int lq = lane >> 4, lc = lane & 15;
  const int wm = wave >> 1, wn = wave & 1;

  const int sr = tid >> 1;
  const int sh = (tid & 1) * 16;
  const int m  = blockIdx.x * 128 + sr;
  const float* arow = x + ((size_t)(m & 63) * T_FULL + (size_t)(t0 + (m >> 6))) * IDIM;
  const float* brow = w_ih0 + (size_t)(blockIdx.y * 128 + sr) * GD;

  floatx4 acc[4][4];
  #pragma unroll
  for (int i = 0; i < 4; ++i)
    #pragma unroll
    for (int j = 0; j < 4; ++j) acc[i][j] = splat4(0.f);

  for (int kk = 0; kk < IDIM; kk += 32) {
    __syncthreads();
    #pragma unroll
    for (int kb = 0; kb < 2; ++kb) {
      const int k0  = sh + kb * 8;
      const int gis = (k0 >> 3) ^ ((sr >> 2) & 3);
      *(half8*)((char*)As + sr * 64 + gis * 16) = cvt8(arow + kk + k0);
      *(half8*)((char*)Bs + sr * 64 + gis * 16) = cvt8(brow + kk + k0);
    }
    __syncthreads();
    half8 af[4], bf[4];
    #pragma unroll
    for (int ms = 0; ms < 4; ++ms) {
      const int r = wm * 64 + ms * 16 + lc;
      af[ms] = *(const half8*)((char*)As + r * 64 + ((lq ^ ((r >> 2) & 3)) * 16));
    }
    #pragma unroll
    for (int ns = 0; ns < 4; ++ns) {
      const int r = wn * 64 + ns * 16 + lc;
      bf[ns] = *(const half8*)((char*)Bs + r * 64 + ((lq ^ ((r >> 2) & 3)) * 16));
    }
    #pragma unroll
    for (int ms = 0; ms < 4; ++ms)
      #pragma unroll
      for (int ns = 0; ns < 4; ++ns)
        acc[ms][ns] = __builtin_amdgcn_mfma_f32_16x16x32_f16(af[ms], bf[ns], acc[ms][ns], 0, 0, 0);
  }

  #pragma unroll
  for (int ms = 0; ms < 4; ++ms)
    #pragma unroll
    for (int ns = 0; ns < 4; ++ns)
      #pragma unroll
      for (int q = 0; q < 4; ++q) {
        const int mloc = blockIdx.x * 128 + wm * 64 + ms * 16 + lq * 4 + q;
        const int gp   = blockIdx.y * 128 + wn * 64 + ns * 16 + lc;
        const int t = mloc >> 6, b = mloc & 63;
        const int gate = gp >> 8, cch = gp & 255;
        Xw[(((size_t)t * NBLK + (cch >> 4)) * 3 + gate) * 1024 + b * 16 + (cch & 15)]
            = (_Float16)acc[ms][ns][q];
      }
}

// ---------------------------------------------------------------------------
// Device-coherent LL packet exchange (PROVEN in round 2): packet = {2 x f16,
// 32-bit step tag} in one aligned 8B word, stored/loaded with sc0 sc1.
// New: one-shot load with tag verify (fast path) + per-step counter spin
// (slow path) instead of re-streaming packets while polling.
// ---------------------------------------------------------------------------
__device__ __forceinline__ bool load_packets(const char* __restrict__ pb, int boff,
                                             unsigned exp, half8* __restrict__ out) {
  uintx4 A[16];
  #pragma unroll
  for (int f = 0; f < 8; ++f) {
    const char* p0 = pb + boff + f * 128;
    asm volatile("global_load_dwordx4 %0, %1, off sc0 sc1"
                 : "=v"(A[2 * f]) : "v"(p0) : "memory");
    asm volatile("global_load_dwordx4 %0, %1, off sc0 sc1"
                 : "=v"(A[2 * f + 1]) : "v"(p0 + 16) : "memory");
  }
  asm volatile("s_waitcnt vmcnt(0)" ::: "memory");
  __builtin_amdgcn_sched_barrier(0);
  bool ok = true;
  #pragma unroll
  for (int j = 0; j < 16; ++j) ok = ok && (A[j].y == exp) && (A[j].w == exp);
  ok = (bool)__all((int)ok);
  #pragma unroll
  for (int f = 0; f < 8; ++f) {
    uintx4 t;
    t.x = A[2 * f].x;     t.y = A[2 * f].z;
    t.z = A[2 * f + 1].x; t.w = A[2 * f + 1].z;
    out[f] = __builtin_bit_cast(half8, t);
  }
  return ok;
}

__device__ __forceinline__ void spin_ctr(unsigned* p, unsigned want) {
  int cap = 1 << 20;
  for (;;) {
    unsigned v;
    asm volatile("global_load_dword %0, %1, off sc0 sc1\n\ts_waitcnt vmcnt(0)"
                 : "=v"(v) : "v"(p) : "memory");
    if (v >= want || --cap <= 0) break;
    __builtin_amdgcn_s_sleep(1);
  }
}

__device__ __forceinline__ void get_packets(const char* __restrict__ pb, int boff,
                                            unsigned exp, half8* __restrict__ out,
                                            unsigned* ctr) {
  if (load_packets(pb, boff, exp, out)) return;   // fast path: producers ahead
  spin_ctr(ctr, NBLK);                            // wait "all 16 published"
  int cap = 256;
  while (!load_packets(pb, boff, exp, out) && --cap > 0) {}
}

__device__ __forceinline__ void publish4(char* __restrict__ base, int wave, int lq, int lc,
                                         int blk, unsigned tag, const float* __restrict__ hv) {
  float pv[4];
  #pragma unroll
  for (int q = 0; q < 4; ++q) pv[q] = __shfl_xor(hv[q], 1, 64);
  unsigned dq[4];
  #pragma unroll
  for (int q = 0; q < 4; ++q) {
    _Float16 a = (_Float16)hv[q], p = (_Float16)pv[q];
    unsigned au = __builtin_bit_cast(unsigned short, a);
    unsigned pu = __builtin_bit_cast(unsigned short, p);
    dq[q] = (lc & 1) ? (pu | (au << 16)) : (au | (pu << 16));
  }
  const int q0 = (lc & 1) ? 2 : 0;
  #pragma unroll
  for (int s = 0; s < 2; ++s) {
    const int q = q0 + s;
    char* addr = base + (((wave * 16 + lq * 4 + q) * 128) + blk * 8 + (lc >> 1)) * 8;
    uintx2 v; v.x = dq[q]; v.y = tag;
    asm volatile("global_store_dwordx2 %0, %1, off sc0 sc1"
                 :: "v"(addr), "v"(v) : "memory");
  }
}

// ---------------------------------------------------------------------------
// Persistent recurrent kernel: 16 blocks x 256 threads. Block owns 16
// channels; wave owns 16 batches. Free-running on LL data dependencies;
// per-step counters (ctrB = h0(t) published, ctrA = step t fully published)
// provide the slow-path wakeup.
// ---------------------------------------------------------------------------
__global__ __launch_bounds__(256, 1)
void rec_step(const float* __restrict__ w_ih0, const float* __restrict__ w_hh0,
              const float* __restrict__ w_ih1, const float* __restrict__ w_hh1,
              const float* __restrict__ b_ih0, const float* __restrict__ b_hh0,
              const float* __restrict__ b_ih1, const float* __restrict__ b_hh1,
              const float* __restrict__ embed_w, const float* __restrict__ embed_b,
              const float* __restrict__ proj_w, const float* __restrict__ proj_b,
              const _Float16* __restrict__ Xw, float* __restrict__ out,
              char* h0b, char* h1b, unsigned* ctrA, unsigned* ctrB,
              int t0, int Tc, int lastChunk) {
  const int tid  = threadIdx.x;
  const int wave = tid >> 6;
  const int lane = tid & 63;
  const int lq = lane >> 4, lc = lane & 15;
  const int blk = blockIdx.x;
  const int c   = blk * 16 + lc;

  // ---- weights in registers (f16 MFMA fragments)
  half8 Whh0[3][8], Whh1[3][8], Wih1[3][8], Pj[8];
  #pragma unroll
  for (int g = 0; g < 3; ++g) {
    const int row = g * NCH + c;
    #pragma unroll
    for (int ks = 0; ks < 8; ++ks) {
      const int k0 = ks * 32 + lq * 8;
      Whh0[g][ks] = cvt8(w_hh0 + (size_t)row * NCH + k0);
      Whh1[g][ks] = cvt8(w_hh1 + (size_t)row * NCH + k0);
      Wih1[g][ks] = cvt8(w_ih1 + (size_t)row * NCH + k0);
    }
  }
  #pragma unroll
  for (int ks = 0; ks < 8; ++ks) {
    const int k0 = ks * 32 + lq * 8;
    half8 z;
    #pragma unroll
    for (int j = 0; j < 8; ++j) z[j] = (_Float16)0.f;
    Pj[ks] = (lc < 3) ? cvt8(proj_w + lc * NCH + k0) : z;
  }

  // ---- folded constants
  float Wce[3][3], bi0[3], bh0v[3], bi1v[3], bh1v[3];
  #pragma unroll
  for (int g = 0; g < 3; ++g) {
    const int row = g * NCH + c;
    float a0 = 0.f, a1 = 0.f, a2 = 0.f, ab = b_ih0[row];
    const float* wr = w_ih0 + (size_t)row * GD + IDIM;
    for (int k = 0; k < NCH; ++k) {
      const float w = wr[k];
      a0 += w * embed_w[k * 3 + 0];
      a1 += w * embed_w[k * 3 + 1];
      a2 += w * embed_w[k * 3 + 2];
      ab += w * embed_b[k];
    }
    Wce[g][0] = a0; Wce[g][1] = a1; Wce[g][2] = a2;
    bi0[g] = ab;
    bh0v[g] = b_hh0[row]; bi1v[g] = b_ih1[row]; bh1v[g] = b_hh1[row];
  }
  const float pb = (lc < 3) ? proj_b[lc] : 0.f;

  // ---- state (resume from previous chunk's packets; prior kernel completed)
  float h0st[4] = {0.f, 0.f, 0.f, 0.f};
  float h1st[4] = {0.f, 0.f, 0.f, 0.f};
  if (t0 > 0) {
    const int rpo = ((t0 & 1) ^ 1) * 65536;
    const unsigned long long* p0 = (const unsigned long long*)(h0b + rpo);
    const unsigned long long* p1 = (const unsigned long long*)(h1b + rpo);
    #pragma unroll
    for (int q = 0; q < 4; ++q) {
      const int b   = wave * 16 + lq * 4 + q;
      const int idx = b * 128 + blk * 8 + (lc >> 1);
      unsigned d0 = (unsigned)p0[idx], d1 = (unsigned)p1[idx];
      unsigned short u0 = (lc & 1) ? (unsigned short)(d0 >> 16) : (unsigned short)(d0 & 0xffff);
      unsigned short u1 = (lc & 1) ? (unsigned short)(d1 >> 16) : (unsigned short)(d1 & 0xffff);
      h0st[q] = (float)__builtin_bit_cast(_Float16, u0);
      h1st[q] = (float)__builtin_bit_cast(_Float16, u1);
    }
  }

  const int boff = (wave * 16 + lc) * 1024 + lq * 32;
  floatx4 ag1l[3];
  half8 hf[8];

  for (int lt = 0; lt < Tc; ++lt) {
    const int gt = t0 + lt;
    const int rp = ((gt & 1) ^ 1) * 65536;
    const int wp = (gt & 1) * 65536;
    const unsigned expt = (unsigned)gt;
    unsigned* cA = ctrA + (gt > 0 ? gt - 1 : 0);

    // ======== PHASE 1 ========
    const _Float16* xb = Xw + ((size_t)lt * NBLK + blk) * 3072;
    unsigned short xwu[3][4];
    #pragma unroll
    for (int g = 0; g < 3; ++g)
      #pragma unroll
      for (int q = 0; q < 4; ++q)
        xwu[g][q] = *(const unsigned short*)(xb + g * 1024 + (wave * 16 + lq * 4 + q) * 16 + lc);

    // h1(t-1): gh1 + v-pre
    get_packets(h1b + rp, boff, expt, hf, cA);
    floatx4 av = splat4(pb);
    #pragma unroll
    for (int g = 0; g < 3; ++g) ag1l[g] = splat4(bh1v[g]);
    #pragma unroll
    for (int ks = 0; ks < 8; ++ks) {
      #pragma unroll
      for (int g = 0; g < 3; ++g)
        ag1l[g] = __builtin_amdgcn_mfma_f32_16x16x32_f16(hf[ks], Whh1[g][ks], ag1l[g], 0, 0, 0);
      av = __builtin_amdgcn_mfma_f32_16x16x32_f16(hf[ks], Pj[ks], av, 0, 0, 0);
    }

    // h0(t-1): gh0
    get_packets(h0b + rp, boff, expt, hf, cA);
    floatx4 ah0[3];
    #pragma unroll
    for (int g = 0; g < 3; ++g) ah0[g] = splat4(bh0v[g]);
    #pragma unroll
    for (int ks = 0; ks < 8; ++ks)
      #pragma unroll
      for (int g = 0; g < 3; ++g)
        ah0[g] = __builtin_amdgcn_mfma_f32_16x16x32_f16(hf[ks], Whh0[g][ks], ah0[g], 0, 0, 0);

    // v(t-1) redistribute + out write
    float vv0[4], vv1[4], vv2[4];
    if (gt == 0) {
      #pragma unroll
      for (int q = 0; q < 4; ++q) { vv0[q] = 0.f; vv1[q] = 0.f; vv2[q] = 0.f; }
    } else {
      float sv[4];
      #pragma unroll
      for (int q = 0; q < 4; ++q) sv[q] = (lc < 3) ? sigmoidf_(av[q]) : 0.f;
      if (blk == 0 && lc < 3) {
        #pragma unroll
        for (int q = 0; q < 4; ++q)
          out[((size_t)(wave * 16 + lq * 4 + q) * T_FULL + (gt - 1)) * ODIM + lc] = sv[q];
      }
      #pragma unroll
      for (int q = 0; q < 4; ++q) {
        vv0[q] = __shfl(sv[q], (lq << 4) + 0, 64);
        vv1[q] = __shfl(sv[q], (lq << 4) + 1, 64);
        vv2[q] = __shfl(sv[q], (lq << 4) + 2, 64);
      }
    }

    // layer-0 combine
    float h0n[4];
    #pragma unroll
    for (int q = 0; q < 4; ++q) {
      const float i_r = (float)__builtin_bit_cast(_Float16, xwu[0][q]) + bi0[0]
                        + vv0[q] * Wce[0][0] + vv1[q] * Wce[0][1] + vv2[q] * Wce[0][2];
      const float i_z = (float)__builtin_bit_cast(_Float16, xwu[1][q]) + bi0[1]
                        + vv0[q] * Wce[1][0] + vv1[q] * Wce[1][1] + vv2[q] * Wce[1][2];
      const float i_n = (float)__builtin_bit_cast(_Float16, xwu[2][q]) + bi0[2]
                        + vv0[q] * Wce[2][0] + vv1[q] * Wce[2][1] + vv2[q] * Wce[2][2];
      const float r = sigmoidf_(i_r + ah0[0][q]);
      const float z = sigmoidf_(i_z + ah0[1][q]);
      const float n = tanhf_(i_n + r * ah0[2][q]);
      h0n[q] = (1.f - z) * n + z * h0st[q];
      h0st[q] = h0n[q];
    }
    publish4(h0b + wp, wave, lq, lc, blk, (unsigned)(gt + 1), h0n);
    __syncthreads();                                   // drains all waves' stores
    if (tid == 0)
      __hip_atomic_fetch_add(&ctrB[gt], 1u, __ATOMIC_RELAXED, __HIP_MEMORY_SCOPE_AGENT);

    // ======== PHASE 2 ========
    get_packets(h0b + wp, boff, (unsigned)(gt + 1), hf, &ctrB[gt]);
    floatx4 ai1[3];
    #pragma unroll
    for (int g = 0; g < 3; ++g) ai1[g] = splat4(bi1v[g]);
    #pragma unroll
    for (int ks = 0; ks < 8; ++ks)
      #pragma unroll
      for (int g = 0; g < 3; ++g)
        ai1[g] = __builtin_amdgcn_mfma_f32_16x16x32_f16(hf[ks], Wih1[g][ks], ai1[g], 0, 0, 0);

    float h1n[4];
    #pragma unroll
    for (int q = 0; q < 4; ++q) {
      const float r = sigmoidf_(ai1[0][q] + ag1l[0][q]);
      const float z = sigmoidf_(ai1[1][q] + ag1l[1][q]);
      const float n = tanhf_(ai1[2][q] + r * ag1l[2][q]);
      h1n[q] = (1.f - z) * n + z * h1st[q];
      h1st[q] = h1n[q];
    }
    publish4(h1b + wp, wave, lq, lc, blk, (unsigned)(gt + 1), h1n);
    __syncthreads();
    if (tid == 0)
      __hip_atomic_fetch_add(&ctrA[gt], 1u, __ATOMIC_RELAXED, __HIP_MEMORY_SCOPE_AGENT);
  }

  // tail: final v(T-1)
  if (lastChunk && blk == 0) {
    const int tl = t0 + Tc - 1;
    get_packets(h1b + ((tl & 1) * 65536), boff, (unsigned)(tl + 1), hf, &ctrA[tl]);
    floatx4 av = splat4(pb);
    #pragma unroll
    for (int ks = 0; ks < 8; ++ks)
      av = __builtin_amdgcn_mfma_f32_16x16x32_f16(hf[ks], Pj[ks], av, 0, 0, 0);
    if (lc < 3) {
      #pragma unroll
      for (int q = 0; q < 4; ++q)
        out[((size_t)(wave * 16 + lq * 4 + q) * T_FULL + (T_FULL - 1)) * ODIM + lc]
            = sigmoidf_(av[q]);
    }
  }
}

extern "C" void kernel_launch(void* const* d_in, const int* in_sizes, int n_in,
                              void* d_out, int out_size, void* d_ws, size_t ws_size,
                              hipStream_t stream) {
  const float* x       = (const float*)d_in[0];
  const float* embed_w = (const float*)d_in[1];
  const float* embed_b = (const float*)d_in[2];
  const float* w_ih0   = (const float*)d_in[3];
  const float* w_hh0   = (const float*)d_in[4];
  const float* b_ih0   = (const float*)d_in[5];
  const float* b_hh0   = (const float*)d_in[6];
  const float* w_ih1   = (const float*)d_in[7];
  const float* w_hh1   = (const float*)d_in[8];
  const float* b_ih1   = (const float*)d_in[9];
  const float* b_hh1   = (const float*)d_in[10];
  const float* proj_w  = (const float*)d_in[11];
  const float* proj_b  = (const float*)d_in[12];
  float* out = (float*)d_out;

  char* ws = (char*)d_ws;
  char* h0b = ws;                               // 2 parity x 64KB packets
  char* h1b = ws + 131072;                      // 2 parity x 64KB packets
  unsigned* ctrA = (unsigned*)(ws + 262144);    // 1024 x 4B step counters
  unsigned* ctrB = (unsigned*)(ws + 266240);    // 1024 x 4B step counters
  _Float16* Xw = (_Float16*)(ws + 270336);

  const size_t per_t = (size_t)NBATCH * GD * sizeof(_Float16);  // 98304 B
  size_t xw_avail = (ws_size > 270336) ? (ws_size - 270336) : 0;
  long maxTc = (long)(xw_avail / per_t);
  int Tc = 2;
  while ((long)Tc * 2 <= maxTc && Tc * 2 <= T_FULL) Tc *= 2;

  // zero packets + counters (tag 0 == "step -1 valid, data 0")
  hipMemsetAsync(ws, 0, 270336, stream);

  for (int t0 = 0; t0 < T_FULL; t0 += Tc) {
    dim3 g1(Tc * NBATCH / 128, GD / 128);
    xw_gemm<<<g1, 256, 0, stream>>>(x, w_ih0, Xw, t0, Tc);
    rec_step<<<NBLK, 256, 0, stream>>>(w_ih0, w_hh0, w_ih1, w_hh1,
                                       b_ih0, b_hh0, b_ih1, b_hh1,
                                       embed_w, embed_b, proj_w, proj_b,
                                       Xw, out, h0b, h1b, ctrA, ctrB,
                                       t0, Tc, (t0 + Tc) >= T_FULL ? 1 : 0);
  }
}